// Round 11
// baseline (292.001 us; speedup 1.0000x reference)
//
#include <hip/hip_runtime.h>
#include <hip/hip_bf16.h>

// ---------------- types & helpers ----------------
typedef __bf16 bf16x8 __attribute__((ext_vector_type(8)));
typedef __bf16 bf16x4 __attribute__((ext_vector_type(4)));
typedef float  f32x4  __attribute__((ext_vector_type(4)));

#define LOG2E 1.44269504088896340f

static __device__ __forceinline__ unsigned short f2bf_bits(float f) {
  unsigned u = __builtin_bit_cast(unsigned, f);
  u = u + 0x7FFFu + ((u >> 16) & 1u);   // RNE
  return (unsigned short)(u >> 16);
}
static __device__ __forceinline__ __bf16 to_bf16(float f) {
  unsigned short s = f2bf_bits(f);
  return __builtin_bit_cast(__bf16, s);
}
static __device__ __forceinline__ float fast_sigmoid(float x) {
  return __builtin_amdgcn_rcpf(1.f + __builtin_amdgcn_exp2f(-LOG2E * x));
}
static __device__ __forceinline__ float softplus_f(float x) {
  float m = fmaxf(x, 0.f);
  float e = __builtin_amdgcn_exp2f(-LOG2E * fabsf(x));
  return fmaf(__builtin_amdgcn_logf(1.f + e), 1.f / LOG2E, m);
}

// ---------------- cast f32 -> bf16 (8 segments) ----------------
struct CastSeg { const float* src; __bf16* dst; int n4; };
struct CastArgs { CastSeg s[8]; };

__global__ __launch_bounds__(256) void cast_kernel(CastArgs a) {
  CastSeg seg = a.s[blockIdx.y];
  int idx = blockIdx.x * 256 + threadIdx.x;
  int stride = gridDim.x * 256;
  const float4* src = (const float4*)seg.src;
  bf16x4* dst = (bf16x4*)seg.dst;
  for (int i = idx; i < seg.n4; i += stride) {
    float4 v = src[i];
    bf16x4 o;
    o[0] = to_bf16(v.x); o[1] = to_bf16(v.y);
    o[2] = to_bf16(v.z); o[3] = to_bf16(v.w);
    dst[i] = o;
  }
}

// ---------------- GEMM: C[M,N] = A[M,K] @ B[N,K]^T ----------------
// MI: fragment rows per wave /16 (4 -> 128-row block tile, 2 -> 64-row).
// SPLIT: cols 0..1023 -> xiout bf16; cols 1024.. -> silu -> gateout bf16.
// K-loop: explicit 1-step-ahead register prefetch (named buffers, K%64==0).
#define LOADK(AF, BF, kk)                                              \
  do {                                                                 \
    _Pragma("unroll")                                                  \
    for (int mi = 0; mi < MI; ++mi)                                    \
      AF[mi] = *(const bf16x8*)(Ap + (size_t)(mi * 16) * K + (kk));    \
    _Pragma("unroll")                                                  \
    for (int ni = 0; ni < 4; ++ni)                                     \
      BF[ni] = *(const bf16x8*)(Bp[ni] + (kk));                        \
  } while (0)

#define MFMAK(AF, BF)                                                  \
  do {                                                                 \
    _Pragma("unroll")                                                  \
    for (int mi = 0; mi < MI; ++mi)                                    \
      _Pragma("unroll")                                                \
      for (int ni = 0; ni < 4; ++ni)                                   \
        acc[mi][ni] = __builtin_amdgcn_mfma_f32_16x16x32_bf16(         \
            AF[mi], BF[ni], acc[mi][ni], 0, 0, 0);                     \
  } while (0)

template<typename OutT, bool BIAS, bool RESID, bool SPLIT, int MI>
__global__ __launch_bounds__(256) void gemm_bt(
    const __bf16* __restrict__ A, long long sAz,
    const __bf16* __restrict__ B0, const __bf16* __restrict__ B1,
    OutT* __restrict__ C, long long sCz, int ldc,
    int N, int K,
    const float* __restrict__ bias, const float* __restrict__ resid, int ldr,
    __bf16* __restrict__ xiout, __bf16* __restrict__ gateout, long long sXz)
{
  const __bf16* B = (blockIdx.z == 0) ? B0 : B1;
  A += (size_t)blockIdx.z * (size_t)sAz;
  C += (size_t)blockIdx.z * (size_t)sCz;
  if (SPLIT) {
    xiout   += (size_t)blockIdx.z * (size_t)sXz;
    gateout += (size_t)blockIdx.z * (size_t)sXz;
  }
  int lane = threadIdx.x & 63;
  int wid  = threadIdx.x >> 6;
  int rowBase = blockIdx.y * (MI * 32) + (wid >> 1) * (MI * 16);
  int colBase = blockIdx.x * 128 + (wid & 1) * 64;
  int lr = lane & 15;
  int lk = (lane >> 4) << 3;           // k-offset within 32-chunk
  const __bf16* Ap = A + (size_t)(rowBase + lr) * K + lk;
  const __bf16* Bp[4];
  #pragma unroll
  for (int ni = 0; ni < 4; ++ni) {
    int br = colBase + ni * 16 + lr;
    if (br > N - 1) br = N - 1;        // clamp (stores masked below)
    Bp[ni] = B + (size_t)br * K + lk;
  }
  f32x4 acc[MI][4] = {};
  bf16x8 aF0[MI], bF0[4], aF1[MI], bF1[4];
  LOADK(aF0, bF0, 0);
  for (int k = 0; k < K; k += 64) {
    LOADK(aF1, bF1, k + 32);
    MFMAK(aF0, bF0);
    if (k + 64 < K) LOADK(aF0, bF0, k + 64);
    MFMAK(aF1, bF1);
  }
  int crow = rowBase + ((lane >> 4) << 2);
  int ccol = colBase + lr;
  #pragma unroll
  for (int mi = 0; mi < MI; ++mi) {
    #pragma unroll
    for (int ni = 0; ni < 4; ++ni) {
      int c = ccol + ni * 16;
      if (c < N) {
        #pragma unroll
        for (int j = 0; j < 4; ++j) {
          int r = crow + mi * 16 + j;
          float v = acc[mi][ni][j];
          if (SPLIT) {
            if (c < 1024) xiout[(size_t)r * 1024 + c] = to_bf16(v);
            else          gateout[(size_t)r * 1024 + (c - 1024)] =
                              to_bf16(v * fast_sigmoid(v));
          } else {
            if (BIAS)  v += bias[c];
            if (RESID) v += resid[(size_t)r * ldr + c];
            if constexpr (sizeof(OutT) == 2) C[(size_t)r * ldc + c] = to_bf16(v);
            else                             C[(size_t)r * ldc + c] = v;
          }
        }
      }
    }
  }
}

// ---------------- causal depthwise conv (both directions) + SiLU ------------
#define CT 16
__global__ __launch_bounds__(256) void conv_silu_kernel(
    const __bf16* __restrict__ xiraw, // [dir][2048][1024] bf16
    const float* __restrict__ f_cw, const float* __restrict__ f_cb,
    const float* __restrict__ b_cw, const float* __restrict__ b_cb,
    __bf16* __restrict__ xi16)        // [dir][2048][1024]
{
  int d  = blockIdx.x * 256 + threadIdx.x;   // 0..1023
  int t0 = blockIdx.y * CT;
  int dir = blockIdx.z >> 1, b = blockIdx.z & 1;
  const float* cw = dir ? b_cw : f_cw;
  const float* cb = dir ? b_cb : f_cb;
  float w0 = cw[d*4+0], w1 = cw[d*4+1], w2 = cw[d*4+2], w3 = cw[d*4+3];
  float bias = cb[d];
  size_t rowBase = (size_t)dir * 2048 + (size_t)b * 1024;
  const __bf16* xp = xiraw + rowBase * 1024 + d;
  __bf16* o16 = xi16 + rowBase * 1024 + d;
  float xv[CT + 3];
  if (dir == 0) {
    #pragma unroll
    for (int j = 0; j < CT + 3; ++j) {
      int t = t0 - 3 + j;
      xv[j] = (t >= 0) ? (float)xp[(size_t)t * 1024] : 0.f;
    }
    #pragma unroll
    for (int j = 0; j < CT; ++j) {
      int t = t0 + j;
      float v = fmaf(w0, xv[j], fmaf(w1, xv[j+1], fmaf(w2, xv[j+2], fmaf(w3, xv[j+3], bias))));
      float s = v * fast_sigmoid(v);
      o16[(size_t)t * 1024] = to_bf16(s);
    }
  } else {
    #pragma unroll
    for (int j = 0; j < CT + 3; ++j) {
      int t = t0 + j;
      xv[j] = (t < 1024) ? (float)xp[(size_t)t * 1024] : 0.f;
    }
    #pragma unroll
    for (int j = 0; j < CT; ++j) {
      int t = t0 + j;
      float v = fmaf(w3, xv[j], fmaf(w2, xv[j+1], fmaf(w1, xv[j+2], fmaf(w0, xv[j+3], bias))));
      float s = v * fast_sigmoid(v);
      o16[(size_t)t * 1024] = to_bf16(s);
    }
  }
}

// ---------------- G2 split-K: partial[dir][slice][2048][64] -----------------
__global__ __launch_bounds__(256) void g2_kernel(
    const __bf16* __restrict__ A,     // xi16 [dir][2048][1024]
    const __bf16* __restrict__ B0, const __bf16* __restrict__ B1, // [64][1024]
    float* __restrict__ partial)      // [dir][4][2048][64]
{
  int slice = blockIdx.x;
  int mt = blockIdx.y;
  int dir = blockIdx.z;
  const __bf16* B = dir ? B1 : B0;
  const __bf16* Ad = A + (size_t)dir * 2048 * 1024;
  int lane = threadIdx.x & 63, wid = threadIdx.x >> 6;
  int rowBase = mt * 64 + wid * 16;
  int lr = lane & 15, lk = (lane >> 4) << 3;
  int k0 = slice * 256;
  const __bf16* Ap = Ad + (size_t)(rowBase + lr) * 1024 + k0 + lk;
  const __bf16* Bp[4];
  #pragma unroll
  for (int ni = 0; ni < 4; ++ni)
    Bp[ni] = B + (size_t)(ni * 16 + lr) * 1024 + k0 + lk;
  f32x4 acc[4] = {};
  #pragma unroll
  for (int k = 0; k < 256; k += 32) {
    bf16x8 aF = *(const bf16x8*)(Ap + k);
    #pragma unroll
    for (int ni = 0; ni < 4; ++ni) {
      bf16x8 bF = *(const bf16x8*)(Bp[ni] + k);
      acc[ni] = __builtin_amdgcn_mfma_f32_16x16x32_bf16(aF, bF, acc[ni], 0, 0, 0);
    }
  }
  int crow = rowBase + ((lane >> 4) << 2);
  float* out = partial + ((size_t)dir * 4 + slice) * 2048 * 64;
  #pragma unroll
  for (int ni = 0; ni < 4; ++ni)
    #pragma unroll
    for (int j = 0; j < 4; ++j)
      out[(size_t)(crow + j) * 64 + ni * 16 + lr] = acc[ni][j];
}

// reduce 4 K-slices -> xdbl [4096][64]
__global__ __launch_bounds__(256) void g2red_kernel(
    const float4* __restrict__ partial, float4* __restrict__ xdbl)
{
  int idx = blockIdx.x * 256 + threadIdx.x;  // 0..65535 float4 units
  int dir = idx >> 15;
  int rest = idx & 32767;
  const float4* p = partial + (size_t)dir * 4 * 32768 + rest;
  float4 a = p[0], b = p[32768], c = p[2 * 32768], d = p[3 * 32768];
  float4 s;
  s.x = a.x + b.x + c.x + d.x;
  s.y = a.y + b.y + c.y + d.y;
  s.z = a.z + b.z + c.z + d.z;
  s.w = a.w + b.w + c.w + d.w;
  xdbl[idx] = s;
}

// ---------------- delta precompute: bf16 [4096][1024] -----------------------
__global__ __launch_bounds__(256) void delta_kernel(
    const float* __restrict__ xdbl,   // [4096][64], dt = cols 0..31
    const float* __restrict__ f_dtw, const float* __restrict__ f_dtb,
    const float* __restrict__ b_dtw, const float* __restrict__ b_dtb,
    __bf16* __restrict__ delta16)     // [4096][1024]
{
  int d = blockIdx.x * 256 + threadIdx.x;
  int dir = blockIdx.z;
  const float* dtw = (dir ? b_dtw : f_dtw) + d * 32;
  float w[32];
  #pragma unroll
  for (int k = 0; k < 32; ++k) w[k] = dtw[k];
  float dtb = (dir ? b_dtb : f_dtb)[d];
  int row0 = dir * 2048 + blockIdx.y * 16;
  #pragma unroll
  for (int r = 0; r < 16; ++r) {
    int row = row0 + r;
    const float* xr = xdbl + (size_t)row * 64;   // block-uniform -> s_load
    float acc = dtb;
    #pragma unroll
    for (int k = 0; k < 32; ++k) acc = fmaf(w[k], xr[k], acc);
    delta16[(size_t)row * 1024 + d] = to_bf16(softplus_f(acc));
  }
}

// ---------------- chunked parallel scan ------------------------------------
#define NC 64
#define CL 16

__global__ __launch_bounds__(256) void scan_part1(
    const __bf16* __restrict__ delta16, const __bf16* __restrict__ xi16,
    const float* __restrict__ xdbl,   // [4096][64] (B 32+n)
    const float* __restrict__ f_Alog, const float* __restrict__ b_Alog,
    float4* __restrict__ aProd, float4* __restrict__ hPart) // [zb][NC][1024][16]
{
  int d = blockIdx.x * 256 + threadIdx.x;   // 0..1023
  int g = blockIdx.y;
  int zb = blockIdx.z;
  int dir = zb >> 1, b = zb & 1;
  const float* Alog = (dir ? b_Alog : f_Alog) + d * 16;
  float As[16];
  #pragma unroll
  for (int n = 0; n < 16; ++n)
    As[n] = -__builtin_amdgcn_exp2f(LOG2E * Alog[n]) * LOG2E;
  int base = dir * 2048 + b * 1024;
  float h[16], A[16];
  #pragma unroll
  for (int n = 0; n < 16; ++n) { h[n] = 0.f; A[n] = 1.f; }
  #pragma unroll
  for (int j = 0; j < CL; ++j) {
    int tau = g * CL + j;
    int row = base + (dir ? (1023 - tau) : tau);
    const float* xr = xdbl + (size_t)row * 64;   // block-uniform -> s_load
    float del = (float)delta16[(size_t)row * 1024 + d];
    float xi  = (float)xi16[(size_t)row * 1024 + d];
    float dx = del * xi;
    #pragma unroll
    for (int n = 0; n < 16; ++n) {
      float dA = __builtin_amdgcn_exp2f(del * As[n]);
      h[n] = fmaf(dA, h[n], dx * xr[32 + n]);
      A[n] *= dA;
    }
  }
  size_t o = (((size_t)zb * NC + g) * 1024 + d) * 4;   // float4 units
  #pragma unroll
  for (int q = 0; q < 4; ++q) {
    aProd[o + q] = float4{A[q*4+0], A[q*4+1], A[q*4+2], A[q*4+3]};
    hPart[o + q] = float4{h[q*4+0], h[q*4+1], h[q*4+2], h[q*4+3]};
  }
}

__global__ __launch_bounds__(256) void scan_combine(
    const float* __restrict__ aProd, const float* __restrict__ hPart,
    float* __restrict__ hIn)
{
  int idx = blockIdx.x * 256 + threadIdx.x;   // 0..65535
  int zb = idx >> 14;
  int dn = idx & 16383;
  float H = 0.f;
  #pragma unroll 8
  for (int g = 0; g < NC; ++g) {
    size_t o = ((size_t)zb * NC + g) * 16384 + dn;
    float a = aProd[o];
    float hp = hPart[o];
    hIn[o] = H;
    H = fmaf(a, H, hp);
  }
}

__global__ __launch_bounds__(256) void scan_part3(
    const __bf16* __restrict__ delta16, const __bf16* __restrict__ xi16,
    const float* __restrict__ xdbl,   // (B 32+n, C 48+n)
    const __bf16* __restrict__ gatebf,// [4096][1024]
    const float* __restrict__ f_Alog, const float* __restrict__ b_Alog,
    const float* __restrict__ f_D, const float* __restrict__ b_D,
    const float* __restrict__ hIn,    // [zb][NC][1024][16]
    __bf16* __restrict__ yout)        // [dir][2048][1024]
{
  int d = blockIdx.x * 256 + threadIdx.x;
  int g = blockIdx.y;
  int zb = blockIdx.z;
  int dir = zb >> 1, b = zb & 1;
  float Dv = (dir ? b_D : f_D)[d];
  const float* Alog = (dir ? b_Alog : f_Alog) + d * 16;
  float As[16];
  #pragma unroll
  for (int n = 0; n < 16; ++n)
    As[n] = -__builtin_amdgcn_exp2f(LOG2E * Alog[n]) * LOG2E;
  float h[16];
  const float4* hi4 = (const float4*)(hIn + (((size_t)zb * NC + g) * 1024 + d) * 16);
  #pragma unroll
  for (int q = 0; q < 4; ++q) {
    float4 hv = hi4[q];
    h[q*4+0] = hv.x; h[q*4+1] = hv.y; h[q*4+2] = hv.z; h[q*4+3] = hv.w;
  }
  int base = dir * 2048 + b * 1024;
  #pragma unroll
  for (int j = 0; j < CL; ++j) {
    int tau = g * CL + j;
    int row = base + (dir ? (1023 - tau) : tau);
    const float* xr = xdbl + (size_t)row * 64;   // block-uniform -> s_load
    float del = (float)delta16[(size_t)row * 1024 + d];
    float xi  = (float)xi16[(size_t)row * 1024 + d];
    float dx = del * xi;
    float ps = 0.f;
    #pragma unroll
    for (int n = 0; n < 16; ++n) {
      float dA = __builtin_amdgcn_exp2f(del * As[n]);
      h[n] = fmaf(dA, h[n], dx * xr[32 + n]);
      ps = fmaf(h[n], xr[48 + n], ps);
    }
    float gate = (float)gatebf[(size_t)row * 1024 + d];
    float y = fmaf(xi, Dv, ps) * gate;
    yout[(size_t)row * 1024 + d] = to_bf16(y);
  }
}

// ---------------- LayerNorm over last dim (512) -----------------------------
__global__ __launch_bounds__(256) void ln_kernel(
    const float* __restrict__ r, const float* __restrict__ g,
    const float* __restrict__ beta, float* __restrict__ out)
{
  int row = blockIdx.x;
  int tid = threadIdx.x;
  const float* rp = r + (size_t)row * 512;
  float v0 = rp[tid], v1 = rp[tid + 256];
  float s = v0 + v1;
  float q = fmaf(v0, v0, v1 * v1);
  #pragma unroll
  for (int m = 1; m < 64; m <<= 1) {
    s += __shfl_xor(s, m, 64);
    q += __shfl_xor(q, m, 64);
  }
  __shared__ float ls[4], lq[4];
  int wid = tid >> 6;
  if ((tid & 63) == 0) { ls[wid] = s; lq[wid] = q; }
  __syncthreads();
  s = ls[0] + ls[1] + ls[2] + ls[3];
  q = lq[0] + lq[1] + lq[2] + lq[3];
  float mu = s * (1.f / 512.f);
  float var = q * (1.f / 512.f) - mu * mu;
  float rs = rsqrtf(var + 1e-5f);
  float* op = out + (size_t)row * 512;
  op[tid]       = (v0 - mu) * rs * g[tid]       + beta[tid];
  op[tid + 256] = (v1 - mu) * rs * g[tid + 256] + beta[tid + 256];
}

// ---------------- host launch ----------------
extern "C" void kernel_launch(void* const* d_in, const int* in_sizes, int n_in,
                              void* d_out, int out_size, void* d_ws, size_t ws_size,
                              hipStream_t stream)
{
  const float* x        = (const float*)d_in[0];
  const float* fusion_w = (const float*)d_in[1];
  const float* fusion_b = (const float*)d_in[2];
  const float* ln_g     = (const float*)d_in[3];
  const float* ln_b     = (const float*)d_in[4];
  const float* f_in_w   = (const float*)d_in[5];
  const float* f_conv_w = (const float*)d_in[6];
  const float* f_conv_b = (const float*)d_in[7];
  const float* f_xproj  = (const float*)d_in[8];
  const float* f_dt_w   = (const float*)d_in[9];
  const float* f_dt_b   = (const float*)d_in[10];
  const float* f_A_log  = (const float*)d_in[11];
  const float* f_D      = (const float*)d_in[12];
  const float* f_out_w  = (const float*)d_in[13];
  const float* b_in_w   = (const float*)d_in[14];
  const float* b_conv_w = (const float*)d_in[15];
  const float* b_conv_b = (const float*)d_in[16];
  const float* b_xproj  = (const float*)d_in[17];
  const float* b_dt_w   = (const float*)d_in[18];
  const float* b_dt_b   = (const float*)d_in[19];
  const float* b_A_log  = (const float*)d_in[20];
  const float* b_D      = (const float*)d_in[21];
  const float* b_out_w  = (const float*)d_in[22];

  char* w = (char*)d_ws;
  auto alloc = [&](size_t bytes) -> char* {
    char* p = w;
    w += (bytes + 255) & ~(size_t)255;
    return p;
  };
  __bf16* xbf    = (__bf16*)alloc((size_t)2048 * 512 * 2);
  __bf16* wInF   = (__bf16*)alloc((size_t)2048 * 512 * 2);
  __bf16* wInB   = (__bf16*)alloc((size_t)2048 * 512 * 2);
  __bf16* xprF   = (__bf16*)alloc((size_t)64 * 1024 * 2);
  __bf16* xprB   = (__bf16*)alloc((size_t)64 * 1024 * 2);
  __bf16* wOutF  = (__bf16*)alloc((size_t)512 * 1024 * 2);
  __bf16* wOutB  = (__bf16*)alloc((size_t)512 * 1024 * 2);
  __bf16* wFus   = (__bf16*)alloc((size_t)512 * 1024 * 2);
  __bf16* xiraw  = (__bf16*)alloc((size_t)2 * 2048 * 1024 * 2);
  __bf16* gatebf = (__bf16*)alloc((size_t)2 * 2048 * 1024 * 2);
  __bf16* xi16   = (__bf16*)alloc((size_t)2 * 2048 * 1024 * 2);
  float*  part2  = (float*)alloc((size_t)2 * 4 * 2048 * 64 * 4);
  float*  xdbl   = (float*)alloc((size_t)2 * 2048 * 64 * 4);
  __bf16* delta16= (__bf16*)alloc((size_t)2 * 2048 * 1024 * 2);
  __bf16* ybf    = (__bf16*)alloc((size_t)2 * 2048 * 1024 * 2);
  __bf16* fin    = (__bf16*)alloc((size_t)2048 * 1024 * 2);
  float*  rbuf   = (float*)alloc((size_t)2048 * 512 * 4);
  float*  aProd  = (float*)alloc((size_t)4 * NC * 16384 * 4);
  float*  hPart  = (float*)alloc((size_t)4 * NC * 16384 * 4);
  float*  hInB   = (float*)alloc((size_t)4 * NC * 16384 * 4);
  (void)ws_size; (void)n_in; (void)in_sizes; (void)out_size;

  // 1) casts
  CastArgs ca;
  ca.s[0] = { x,        xbf,   (2048 * 512) / 4 };
  ca.s[1] = { f_in_w,   wInF,  (2048 * 512) / 4 };
  ca.s[2] = { b_in_w,   wInB,  (2048 * 512) / 4 };
  ca.s[3] = { f_xproj,  xprF,  (64 * 1024) / 4 };
  ca.s[4] = { b_xproj,  xprB,  (64 * 1024) / 4 };
  ca.s[5] = { f_out_w,  wOutF, (512 * 1024) / 4 };
  ca.s[6] = { b_out_w,  wOutB, (512 * 1024) / 4 };
  ca.s[7] = { fusion_w, wFus,  (512 * 1024) / 4 };
  cast_kernel<<<dim3(256, 8), 256, 0, stream>>>(ca);

  // 2) G1 (split): 64x128 tiles (1024 blocks) + register prefetch
  gemm_bt<float, false, false, true, 2><<<dim3(16, 32, 2), 256, 0, stream>>>(
      xbf, 0LL, wInF, wInB, (float*)nullptr, 0LL, 0, 2048, 512,
      nullptr, nullptr, 0, xiraw, gatebf, (long long)2048 * 1024);

  // 3) conv + SiLU -> xi16
  conv_silu_kernel<<<dim3(4, 1024 / CT, 4), 256, 0, stream>>>(
      xiraw, f_conv_w, f_conv_b, b_conv_w, b_conv_b, xi16);

  // 4) G2 split-K x4 + reduce -> xdbl
  g2_kernel<<<dim3(4, 32, 2), 256, 0, stream>>>(xi16, xprF, xprB, part2);
  g2red_kernel<<<dim3(256), 256, 0, stream>>>((const float4*)part2, (float4*)xdbl);

  // 5) delta precompute (bf16)
  delta_kernel<<<dim3(4, 128, 2), 256, 0, stream>>>(
      xdbl, f_dt_w, f_dt_b, b_dt_w, b_dt_b, delta16);

  // 6) chunked scan: pass1 -> combine -> pass3
  scan_part1<<<dim3(4, NC, 4), 256, 0, stream>>>(
      delta16, xi16, xdbl, f_A_log, b_A_log, (float4*)aProd, (float4*)hPart);
  scan_combine<<<dim3(256), 256, 0, stream>>>(aProd, hPart, hInB);
  scan_part3<<<dim3(4, NC, 4), 256, 0, stream>>>(
      delta16, xi16, xdbl, gatebf, f_A_log, b_A_log, f_D, b_D, hInB, ybf);

  // 7) G4: fused_in[:, dir*512:+512] = y @ out_w^T  (N=512, K=1024), 64-row tiles
  gemm_bt<__bf16, false, false, false, 2><<<dim3(4, 32, 2), 256, 0, stream>>>(
      ybf, (long long)2048 * 1024, wOutF, wOutB, fin, 512LL, 1024, 512, 1024,
      nullptr, nullptr, 0, nullptr, nullptr, 0LL);

  // 8) G5: r = x + fused_in @ fusion_w^T + fusion_b  (N=512, K=1024), 64-row tiles
  gemm_bt<float, true, true, false, 2><<<dim3(4, 32, 1), 256, 0, stream>>>(
      fin, 0LL, wFus, wFus, rbuf, 0LL, 512, 512, 1024,
      fusion_b, x, 512, nullptr, nullptr, 0LL);

  // 9) LayerNorm -> d_out
  ln_kernel<<<2048, 256, 0, stream>>>(rbuf, ln_g, ln_b, (float*)d_out);
}

// Round 12
// 262.787 us; speedup vs baseline: 1.1112x; 1.1112x over previous
//
#include <hip/hip_runtime.h>
#include <hip/hip_bf16.h>

// ---------------- types & helpers ----------------
typedef __bf16 bf16x8 __attribute__((ext_vector_type(8)));
typedef __bf16 bf16x4 __attribute__((ext_vector_type(4)));
typedef float  f32x4  __attribute__((ext_vector_type(4)));

#define LOG2E 1.44269504088896340f

static __device__ __forceinline__ unsigned short f2bf_bits(float f) {
  unsigned u = __builtin_bit_cast(unsigned, f);
  u = u + 0x7FFFu + ((u >> 16) & 1u);   // RNE
  return (unsigned short)(u >> 16);
}
static __device__ __forceinline__ __bf16 to_bf16(float f) {
  unsigned short s = f2bf_bits(f);
  return __builtin_bit_cast(__bf16, s);
}
static __device__ __forceinline__ float fast_sigmoid(float x) {
  return __builtin_amdgcn_rcpf(1.f + __builtin_amdgcn_exp2f(-LOG2E * x));
}
static __device__ __forceinline__ float softplus_f(float x) {
  float m = fmaxf(x, 0.f);
  float e = __builtin_amdgcn_exp2f(-LOG2E * fabsf(x));
  return fmaf(__builtin_amdgcn_logf(1.f + e), 1.f / LOG2E, m);
}

// ---------------- cast f32 -> bf16 (8 segments) ----------------
struct CastSeg { const float* src; __bf16* dst; int n4; };
struct CastArgs { CastSeg s[8]; };

__global__ __launch_bounds__(256) void cast_kernel(CastArgs a) {
  CastSeg seg = a.s[blockIdx.y];
  int idx = blockIdx.x * 256 + threadIdx.x;
  int stride = gridDim.x * 256;
  const float4* src = (const float4*)seg.src;
  bf16x4* dst = (bf16x4*)seg.dst;
  for (int i = idx; i < seg.n4; i += stride) {
    float4 v = src[i];
    bf16x4 o;
    o[0] = to_bf16(v.x); o[1] = to_bf16(v.y);
    o[2] = to_bf16(v.z); o[3] = to_bf16(v.w);
    dst[i] = o;
  }
}

// ---------------- LDS double-buffered GEMM: C[M,N] = A[M,K] @ B[N,K]^T ------
// 128x128 tile, BK=32, 4 waves (2x2 of 64x64). Reg-staged LDS, row stride 40
// elems (80B = 20 banks: conflict-free ds_read_b128; 16B-aligned).
// Requires N % 128 == 0, K % 32 == 0.
#define LDSTRIDE 40
template<typename OutT, bool BIAS, bool RESID, bool SPLIT>
__global__ __launch_bounds__(256) void gemm_lds(
    const __bf16* __restrict__ A, long long sAz,
    const __bf16* __restrict__ B0, const __bf16* __restrict__ B1,
    OutT* __restrict__ C, long long sCz, int ldc,
    int N, int K,
    const float* __restrict__ bias, const float* __restrict__ resid, int ldr,
    __bf16* __restrict__ xiout, __bf16* __restrict__ gateout, long long sXz)
{
  __shared__ __bf16 ldsA[2][128 * LDSTRIDE];
  __shared__ __bf16 ldsB[2][128 * LDSTRIDE];
  const __bf16* B = (blockIdx.z == 0) ? B0 : B1;
  A += (size_t)blockIdx.z * (size_t)sAz;
  C += (size_t)blockIdx.z * (size_t)sCz;
  if (SPLIT) {
    xiout   += (size_t)blockIdx.z * (size_t)sXz;
    gateout += (size_t)blockIdx.z * (size_t)sXz;
  }
  int tid = threadIdx.x;
  int lane = tid & 63, wid = tid >> 6;
  int wr = wid >> 1, wc = wid & 1;
  int rowTile = blockIdx.y * 128;
  int colTile = blockIdx.x * 128;
  // staging: thread t covers rows t/4 and t/4+64, cols (t%4)*8 .. +8
  int srow = tid >> 2;
  int scol = (tid & 3) << 3;
  const __bf16* Ag  = A + (size_t)(rowTile + srow) * K + scol;
  const __bf16* Ag2 = Ag + (size_t)64 * K;
  const __bf16* Bg  = B + (size_t)(colTile + srow) * K + scol;
  const __bf16* Bg2 = Bg + (size_t)64 * K;
  int sidx = srow * LDSTRIDE + scol;

  auto stageTo = [&](int buf, int k0) {
    bf16x8 a0 = *(const bf16x8*)(Ag + k0);
    bf16x8 a1 = *(const bf16x8*)(Ag2 + k0);
    bf16x8 b0 = *(const bf16x8*)(Bg + k0);
    bf16x8 b1 = *(const bf16x8*)(Bg2 + k0);
    *(bf16x8*)&ldsA[buf][sidx] = a0;
    *(bf16x8*)&ldsA[buf][64 * LDSTRIDE + sidx] = a1;
    *(bf16x8*)&ldsB[buf][sidx] = b0;
    *(bf16x8*)&ldsB[buf][64 * LDSTRIDE + sidx] = b1;
  };

  int lr = lane & 15;
  int lk = (lane >> 4) << 3;
  int aoff = (wr * 64 + lr) * LDSTRIDE + lk;
  int boff = (wc * 64 + lr) * LDSTRIDE + lk;

  f32x4 acc[4][4] = {};
  int nSteps = K >> 5;
  stageTo(0, 0);
  __syncthreads();
  for (int ks = 0; ks < nSteps; ++ks) {
    int cur = ks & 1;
    if (ks + 1 < nSteps) stageTo(cur ^ 1, (ks + 1) << 5);
    bf16x8 aF[4], bF[4];
    #pragma unroll
    for (int mi = 0; mi < 4; ++mi)
      aF[mi] = *(const bf16x8*)&ldsA[cur][aoff + mi * 16 * LDSTRIDE];
    #pragma unroll
    for (int ni = 0; ni < 4; ++ni)
      bF[ni] = *(const bf16x8*)&ldsB[cur][boff + ni * 16 * LDSTRIDE];
    #pragma unroll
    for (int mi = 0; mi < 4; ++mi)
      #pragma unroll
      for (int ni = 0; ni < 4; ++ni)
        acc[mi][ni] = __builtin_amdgcn_mfma_f32_16x16x32_bf16(aF[mi], bF[ni], acc[mi][ni], 0, 0, 0);
    __syncthreads();
  }
  int crow = rowTile + wr * 64 + ((lane >> 4) << 2);
  int ccol = colTile + wc * 64 + lr;
  #pragma unroll
  for (int mi = 0; mi < 4; ++mi) {
    #pragma unroll
    for (int ni = 0; ni < 4; ++ni) {
      int c = ccol + ni * 16;
      #pragma unroll
      for (int j = 0; j < 4; ++j) {
        int r = crow + mi * 16 + j;
        float v = acc[mi][ni][j];
        if (SPLIT) {
          if (c < 1024) xiout[(size_t)r * 1024 + c] = to_bf16(v);
          else          gateout[(size_t)r * 1024 + (c - 1024)] =
                            to_bf16(v * fast_sigmoid(v));
        } else {
          if (BIAS)  v += bias[c];
          if (RESID) v += resid[(size_t)r * ldr + c];
          if constexpr (sizeof(OutT) == 2) C[(size_t)r * ldc + c] = to_bf16(v);
          else                             C[(size_t)r * ldc + c] = v;
        }
      }
    }
  }
}

// ---------------- direct GEMM (G4/G5): C[M,N] = A[M,K] @ B[N,K]^T -----------
#define LOADK(AF, BF, kk)                                              \
  do {                                                                 \
    _Pragma("unroll")                                                  \
    for (int mi = 0; mi < MI; ++mi)                                    \
      AF[mi] = *(const bf16x8*)(Ap + (size_t)(mi * 16) * K + (kk));    \
    _Pragma("unroll")                                                  \
    for (int ni = 0; ni < 4; ++ni)                                     \
      BF[ni] = *(const bf16x8*)(Bp[ni] + (kk));                        \
  } while (0)

#define MFMAK(AF, BF)                                                  \
  do {                                                                 \
    _Pragma("unroll")                                                  \
    for (int mi = 0; mi < MI; ++mi)                                    \
      _Pragma("unroll")                                                \
      for (int ni = 0; ni < 4; ++ni)                                   \
        acc[mi][ni] = __builtin_amdgcn_mfma_f32_16x16x32_bf16(         \
            AF[mi], BF[ni], acc[mi][ni], 0, 0, 0);                     \
  } while (0)

template<typename OutT, bool BIAS, bool RESID, int MI>
__global__ __launch_bounds__(256) void gemm_bt(
    const __bf16* __restrict__ A, long long sAz,
    const __bf16* __restrict__ B0, const __bf16* __restrict__ B1,
    OutT* __restrict__ C, long long sCz, int ldc,
    int N, int K,
    const float* __restrict__ bias, const float* __restrict__ resid, int ldr)
{
  const __bf16* B = (blockIdx.z == 0) ? B0 : B1;
  A += (size_t)blockIdx.z * (size_t)sAz;
  C += (size_t)blockIdx.z * (size_t)sCz;
  int lane = threadIdx.x & 63;
  int wid  = threadIdx.x >> 6;
  int rowBase = blockIdx.y * (MI * 32) + (wid >> 1) * (MI * 16);
  int colBase = blockIdx.x * 128 + (wid & 1) * 64;
  int lr = lane & 15;
  int lk = (lane >> 4) << 3;           // k-offset within 32-chunk
  const __bf16* Ap = A + (size_t)(rowBase + lr) * K + lk;
  const __bf16* Bp[4];
  #pragma unroll
  for (int ni = 0; ni < 4; ++ni) {
    int br = colBase + ni * 16 + lr;
    if (br > N - 1) br = N - 1;        // clamp (stores masked below)
    Bp[ni] = B + (size_t)br * K + lk;
  }
  f32x4 acc[MI][4] = {};
  bf16x8 aF0[MI], bF0[4], aF1[MI], bF1[4];
  LOADK(aF0, bF0, 0);
  for (int k = 0; k < K; k += 64) {
    LOADK(aF1, bF1, k + 32);
    MFMAK(aF0, bF0);
    if (k + 64 < K) LOADK(aF0, bF0, k + 64);
    MFMAK(aF1, bF1);
  }
  int crow = rowBase + ((lane >> 4) << 2);
  int ccol = colBase + lr;
  #pragma unroll
  for (int mi = 0; mi < MI; ++mi) {
    #pragma unroll
    for (int ni = 0; ni < 4; ++ni) {
      int c = ccol + ni * 16;
      if (c < N) {
        #pragma unroll
        for (int j = 0; j < 4; ++j) {
          int r = crow + mi * 16 + j;
          float v = acc[mi][ni][j];
          if (BIAS)  v += bias[c];
          if (RESID) v += resid[(size_t)r * ldr + c];
          if constexpr (sizeof(OutT) == 2) C[(size_t)r * ldc + c] = to_bf16(v);
          else                             C[(size_t)r * ldc + c] = v;
        }
      }
    }
  }
}

// ---------------- causal depthwise conv (both directions) + SiLU ------------
#define CT 16
__global__ __launch_bounds__(256) void conv_silu_kernel(
    const __bf16* __restrict__ xiraw, // [dir][2048][1024] bf16
    const float* __restrict__ f_cw, const float* __restrict__ f_cb,
    const float* __restrict__ b_cw, const float* __restrict__ b_cb,
    __bf16* __restrict__ xi16)        // [dir][2048][1024]
{
  int d  = blockIdx.x * 256 + threadIdx.x;   // 0..1023
  int t0 = blockIdx.y * CT;
  int dir = blockIdx.z >> 1, b = blockIdx.z & 1;
  const float* cw = dir ? b_cw : f_cw;
  const float* cb = dir ? b_cb : f_cb;
  float w0 = cw[d*4+0], w1 = cw[d*4+1], w2 = cw[d*4+2], w3 = cw[d*4+3];
  float bias = cb[d];
  size_t rowBase = (size_t)dir * 2048 + (size_t)b * 1024;
  const __bf16* xp = xiraw + rowBase * 1024 + d;
  __bf16* o16 = xi16 + rowBase * 1024 + d;
  float xv[CT + 3];
  if (dir == 0) {
    #pragma unroll
    for (int j = 0; j < CT + 3; ++j) {
      int t = t0 - 3 + j;
      xv[j] = (t >= 0) ? (float)xp[(size_t)t * 1024] : 0.f;
    }
    #pragma unroll
    for (int j = 0; j < CT; ++j) {
      int t = t0 + j;
      float v = fmaf(w0, xv[j], fmaf(w1, xv[j+1], fmaf(w2, xv[j+2], fmaf(w3, xv[j+3], bias))));
      float s = v * fast_sigmoid(v);
      o16[(size_t)t * 1024] = to_bf16(s);
    }
  } else {
    #pragma unroll
    for (int j = 0; j < CT + 3; ++j) {
      int t = t0 + j;
      xv[j] = (t < 1024) ? (float)xp[(size_t)t * 1024] : 0.f;
    }
    #pragma unroll
    for (int j = 0; j < CT; ++j) {
      int t = t0 + j;
      float v = fmaf(w3, xv[j], fmaf(w2, xv[j+1], fmaf(w1, xv[j+2], fmaf(w0, xv[j+3], bias))));
      float s = v * fast_sigmoid(v);
      o16[(size_t)t * 1024] = to_bf16(s);
    }
  }
}

// ---------------- G2 split-K: partial[dir][slice][2048][64] -----------------
__global__ __launch_bounds__(256) void g2_kernel(
    const __bf16* __restrict__ A,     // xi16 [dir][2048][1024]
    const __bf16* __restrict__ B0, const __bf16* __restrict__ B1, // [64][1024]
    float* __restrict__ partial)      // [dir][4][2048][64]
{
  int slice = blockIdx.x;
  int mt = blockIdx.y;
  int dir = blockIdx.z;
  const __bf16* B = dir ? B1 : B0;
  const __bf16* Ad = A + (size_t)dir * 2048 * 1024;
  int lane = threadIdx.x & 63, wid = threadIdx.x >> 6;
  int rowBase = mt * 64 + wid * 16;
  int lr = lane & 15, lk = (lane >> 4) << 3;
  int k0 = slice * 256;
  const __bf16* Ap = Ad + (size_t)(rowBase + lr) * 1024 + k0 + lk;
  const __bf16* Bp[4];
  #pragma unroll
  for (int ni = 0; ni < 4; ++ni)
    Bp[ni] = B + (size_t)(ni * 16 + lr) * 1024 + k0 + lk;
  f32x4 acc[4] = {};
  #pragma unroll
  for (int k = 0; k < 256; k += 32) {
    bf16x8 aF = *(const bf16x8*)(Ap + k);
    #pragma unroll
    for (int ni = 0; ni < 4; ++ni) {
      bf16x8 bF = *(const bf16x8*)(Bp[ni] + k);
      acc[ni] = __builtin_amdgcn_mfma_f32_16x16x32_bf16(aF, bF, acc[ni], 0, 0, 0);
    }
  }
  int crow = rowBase + ((lane >> 4) << 2);
  float* out = partial + ((size_t)dir * 4 + slice) * 2048 * 64;
  #pragma unroll
  for (int ni = 0; ni < 4; ++ni)
    #pragma unroll
    for (int j = 0; j < 4; ++j)
      out[(size_t)(crow + j) * 64 + ni * 16 + lr] = acc[ni][j];
}

// reduce 4 K-slices -> xdbl [4096][64]
__global__ __launch_bounds__(256) void g2red_kernel(
    const float4* __restrict__ partial, float4* __restrict__ xdbl)
{
  int idx = blockIdx.x * 256 + threadIdx.x;  // 0..65535 float4 units
  int dir = idx >> 15;
  int rest = idx & 32767;
  const float4* p = partial + (size_t)dir * 4 * 32768 + rest;
  float4 a = p[0], b = p[32768], c = p[2 * 32768], d = p[3 * 32768];
  float4 s;
  s.x = a.x + b.x + c.x + d.x;
  s.y = a.y + b.y + c.y + d.y;
  s.z = a.z + b.z + c.z + d.z;
  s.w = a.w + b.w + c.w + d.w;
  xdbl[idx] = s;
}

// ---------------- delta precompute: bf16 [4096][1024] -----------------------
__global__ __launch_bounds__(256) void delta_kernel(
    const float* __restrict__ xdbl,   // [4096][64], dt = cols 0..31
    const float* __restrict__ f_dtw, const float* __restrict__ f_dtb,
    const float* __restrict__ b_dtw, const float* __restrict__ b_dtb,
    __bf16* __restrict__ delta16)     // [4096][1024]
{
  int d = blockIdx.x * 256 + threadIdx.x;
  int dir = blockIdx.z;
  const float* dtw = (dir ? b_dtw : f_dtw) + d * 32;
  float w[32];
  #pragma unroll
  for (int k = 0; k < 32; ++k) w[k] = dtw[k];
  float dtb = (dir ? b_dtb : f_dtb)[d];
  int row0 = dir * 2048 + blockIdx.y * 16;
  #pragma unroll
  for (int r = 0; r < 16; ++r) {
    int row = row0 + r;
    const float* xr = xdbl + (size_t)row * 64;   // block-uniform -> s_load
    float acc = dtb;
    #pragma unroll
    for (int k = 0; k < 32; ++k) acc = fmaf(w[k], xr[k], acc);
    delta16[(size_t)row * 1024 + d] = to_bf16(softplus_f(acc));
  }
}

// ---------------- chunked parallel scan ------------------------------------
#define NC 64
#define CL 16

__global__ __launch_bounds__(256) void scan_part1(
    const __bf16* __restrict__ delta16, const __bf16* __restrict__ xi16,
    const float* __restrict__ xdbl,   // [4096][64] (B 32+n)
    const float* __restrict__ f_Alog, const float* __restrict__ b_Alog,
    float4* __restrict__ aProd, float4* __restrict__ hPart) // [zb][NC][1024][16]
{
  int d = blockIdx.x * 256 + threadIdx.x;   // 0..1023
  int g = blockIdx.y;
  int zb = blockIdx.z;
  int dir = zb >> 1, b = zb & 1;
  const float* Alog = (dir ? b_Alog : f_Alog) + d * 16;
  float As[16];
  #pragma unroll
  for (int n = 0; n < 16; ++n)
    As[n] = -__builtin_amdgcn_exp2f(LOG2E * Alog[n]) * LOG2E;
  int base = dir * 2048 + b * 1024;
  float h[16], A[16];
  #pragma unroll
  for (int n = 0; n < 16; ++n) { h[n] = 0.f; A[n] = 1.f; }
  #pragma unroll
  for (int j = 0; j < CL; ++j) {
    int tau = g * CL + j;
    int row = base + (dir ? (1023 - tau) : tau);
    const float* xr = xdbl + (size_t)row * 64;   // block-uniform -> s_load
    float del = (float)delta16[(size_t)row * 1024 + d];
    float xi  = (float)xi16[(size_t)row * 1024 + d];
    float dx = del * xi;
    #pragma unroll
    for (int n = 0; n < 16; ++n) {
      float dA = __builtin_amdgcn_exp2f(del * As[n]);
      h[n] = fmaf(dA, h[n], dx * xr[32 + n]);
      A[n] *= dA;
    }
  }
  size_t o = (((size_t)zb * NC + g) * 1024 + d) * 4;   // float4 units
  #pragma unroll
  for (int q = 0; q < 4; ++q) {
    aProd[o + q] = float4{A[q*4+0], A[q*4+1], A[q*4+2], A[q*4+3]};
    hPart[o + q] = float4{h[q*4+0], h[q*4+1], h[q*4+2], h[q*4+3]};
  }
}

__global__ __launch_bounds__(256) void scan_combine(
    const float* __restrict__ aProd, const float* __restrict__ hPart,
    float* __restrict__ hIn)
{
  int idx = blockIdx.x * 256 + threadIdx.x;   // 0..65535
  int zb = idx >> 14;
  int dn = idx & 16383;
  float H = 0.f;
  #pragma unroll 8
  for (int g = 0; g < NC; ++g) {
    size_t o = ((size_t)zb * NC + g) * 16384 + dn;
    float a = aProd[o];
    float hp = hPart[o];
    hIn[o] = H;
    H = fmaf(a, H, hp);
  }
}

__global__ __launch_bounds__(256) void scan_part3(
    const __bf16* __restrict__ delta16, const __bf16* __restrict__ xi16,
    const float* __restrict__ xdbl,   // (B 32+n, C 48+n)
    const __bf16* __restrict__ gatebf,// [4096][1024]
    const float* __restrict__ f_Alog, const float* __restrict__ b_Alog,
    const float* __restrict__ f_D, const float* __restrict__ b_D,
    const float* __restrict__ hIn,    // [zb][NC][1024][16]
    __bf16* __restrict__ yout)        // [dir][2048][1024]
{
  int d = blockIdx.x * 256 + threadIdx.x;
  int g = blockIdx.y;
  int zb = blockIdx.z;
  int dir = zb >> 1, b = zb & 1;
  float Dv = (dir ? b_D : f_D)[d];
  const float* Alog = (dir ? b_Alog : f_Alog) + d * 16;
  float As[16];
  #pragma unroll
  for (int n = 0; n < 16; ++n)
    As[n] = -__builtin_amdgcn_exp2f(LOG2E * Alog[n]) * LOG2E;
  float h[16];
  const float4* hi4 = (const float4*)(hIn + (((size_t)zb * NC + g) * 1024 + d) * 16);
  #pragma unroll
  for (int q = 0; q < 4; ++q) {
    float4 hv = hi4[q];
    h[q*4+0] = hv.x; h[q*4+1] = hv.y; h[q*4+2] = hv.z; h[q*4+3] = hv.w;
  }
  int base = dir * 2048 + b * 1024;
  #pragma unroll
  for (int j = 0; j < CL; ++j) {
    int tau = g * CL + j;
    int row = base + (dir ? (1023 - tau) : tau);
    const float* xr = xdbl + (size_t)row * 64;   // block-uniform -> s_load
    float del = (float)delta16[(size_t)row * 1024 + d];
    float xi  = (float)xi16[(size_t)row * 1024 + d];
    float dx = del * xi;
    float ps = 0.f;
    #pragma unroll
    for (int n = 0; n < 16; ++n) {
      float dA = __builtin_amdgcn_exp2f(del * As[n]);
      h[n] = fmaf(dA, h[n], dx * xr[32 + n]);
      ps = fmaf(h[n], xr[48 + n], ps);
    }
    float gate = (float)gatebf[(size_t)row * 1024 + d];
    float y = fmaf(xi, Dv, ps) * gate;
    yout[(size_t)row * 1024 + d] = to_bf16(y);
  }
}

// ---------------- LayerNorm over last dim (512) -----------------------------
__global__ __launch_bounds__(256) void ln_kernel(
    const float* __restrict__ r, const float* __restrict__ g,
    const float* __restrict__ beta, float* __restrict__ out)
{
  int row = blockIdx.x;
  int tid = threadIdx.x;
  const float* rp = r + (size_t)row * 512;
  float v0 = rp[tid], v1 = rp[tid + 256];
  float s = v0 + v1;
  float q = fmaf(v0, v0, v1 * v1);
  #pragma unroll
  for (int m = 1; m < 64; m <<= 1) {
    s += __shfl_xor(s, m, 64);
    q += __shfl_xor(q, m, 64);
  }
  __shared__ float ls[4], lq[4];
  int wid = tid >> 6;
  if ((tid & 63) == 0) { ls[wid] = s; lq[wid] = q; }
  __syncthreads();
  s = ls[0] + ls[1] + ls[2] + ls[3];
  q = lq[0] + lq[1] + lq[2] + lq[3];
  float mu = s * (1.f / 512.f);
  float var = q * (1.f / 512.f) - mu * mu;
  float rs = rsqrtf(var + 1e-5f);
  float* op = out + (size_t)row * 512;
  op[tid]       = (v0 - mu) * rs * g[tid]       + beta[tid];
  op[tid + 256] = (v1 - mu) * rs * g[tid + 256] + beta[tid + 256];
}

// ---------------- host launch ----------------
extern "C" void kernel_launch(void* const* d_in, const int* in_sizes, int n_in,
                              void* d_out, int out_size, void* d_ws, size_t ws_size,
                              hipStream_t stream)
{
  const float* x        = (const float*)d_in[0];
  const float* fusion_w = (const float*)d_in[1];
  const float* fusion_b = (const float*)d_in[2];
  const float* ln_g     = (const float*)d_in[3];
  const float* ln_b     = (const float*)d_in[4];
  const float* f_in_w   = (const float*)d_in[5];
  const float* f_conv_w = (const float*)d_in[6];
  const float* f_conv_b = (const float*)d_in[7];
  const float* f_xproj  = (const float*)d_in[8];
  const float* f_dt_w   = (const float*)d_in[9];
  const float* f_dt_b   = (const float*)d_in[10];
  const float* f_A_log  = (const float*)d_in[11];
  const float* f_D      = (const float*)d_in[12];
  const float* f_out_w  = (const float*)d_in[13];
  const float* b_in_w   = (const float*)d_in[14];
  const float* b_conv_w = (const float*)d_in[15];
  const float* b_conv_b = (const float*)d_in[16];
  const float* b_xproj  = (const float*)d_in[17];
  const float* b_dt_w   = (const float*)d_in[18];
  const float* b_dt_b   = (const float*)d_in[19];
  const float* b_A_log  = (const float*)d_in[20];
  const float* b_D      = (const float*)d_in[21];
  const float* b_out_w  = (const float*)d_in[22];

  char* w = (char*)d_ws;
  auto alloc = [&](size_t bytes) -> char* {
    char* p = w;
    w += (bytes + 255) & ~(size_t)255;
    return p;
  };
  __bf16* xbf    = (__bf16*)alloc((size_t)2048 * 512 * 2);
  __bf16* wInF   = (__bf16*)alloc((size_t)2048 * 512 * 2);
  __bf16* wInB   = (__bf16*)alloc((size_t)2048 * 512 * 2);
  __bf16* xprF   = (__bf16*)alloc((size_t)64 * 1024 * 2);
  __bf16* xprB   = (__bf16*)alloc((size_t)64 * 1024 * 2);
  __bf16* wOutF  = (__bf16*)alloc((size_t)512 * 1024 * 2);
  __bf16* wOutB  = (__bf16*)alloc((size_t)512 * 1024 * 2);
  __bf16* wFus   = (__bf16*)alloc((size_t)512 * 1024 * 2);
  __bf16* xiraw  = (__bf16*)alloc((size_t)2 * 2048 * 1024 * 2);
  __bf16* gatebf = (__bf16*)alloc((size_t)2 * 2048 * 1024 * 2);
  __bf16* xi16   = (__bf16*)alloc((size_t)2 * 2048 * 1024 * 2);
  float*  part2  = (float*)alloc((size_t)2 * 4 * 2048 * 64 * 4);
  float*  xdbl   = (float*)alloc((size_t)2 * 2048 * 64 * 4);
  __bf16* delta16= (__bf16*)alloc((size_t)2 * 2048 * 1024 * 2);
  __bf16* ybf    = (__bf16*)alloc((size_t)2 * 2048 * 1024 * 2);
  __bf16* fin    = (__bf16*)alloc((size_t)2048 * 1024 * 2);
  float*  rbuf   = (float*)alloc((size_t)2048 * 512 * 4);
  float*  aProd  = (float*)alloc((size_t)4 * NC * 16384 * 4);
  float*  hPart  = (float*)alloc((size_t)4 * NC * 16384 * 4);
  float*  hInB   = (float*)alloc((size_t)4 * NC * 16384 * 4);
  (void)ws_size; (void)n_in; (void)in_sizes; (void)out_size;

  // 1) casts
  CastArgs ca;
  ca.s[0] = { x,        xbf,   (2048 * 512) / 4 };
  ca.s[1] = { f_in_w,   wInF,  (2048 * 512) / 4 };
  ca.s[2] = { b_in_w,   wInB,  (2048 * 512) / 4 };
  ca.s[3] = { f_xproj,  xprF,  (64 * 1024) / 4 };
  ca.s[4] = { b_xproj,  xprB,  (64 * 1024) / 4 };
  ca.s[5] = { f_out_w,  wOutF, (512 * 1024) / 4 };
  ca.s[6] = { b_out_w,  wOutB, (512 * 1024) / 4 };
  ca.s[7] = { fusion_w, wFus,  (512 * 1024) / 4 };
  cast_kernel<<<dim3(256, 8), 256, 0, stream>>>(ca);

  // 2) G1 (split, LDS-pipelined 128x128): xi -> xiraw bf16; z -> silu -> gatebf
  gemm_lds<float, false, false, true><<<dim3(16, 16, 2), 256, 0, stream>>>(
      xbf, 0LL, wInF, wInB, (float*)nullptr, 0LL, 0, 2048, 512,
      nullptr, nullptr, 0, xiraw, gatebf, (long long)2048 * 1024);

  // 3) conv + SiLU -> xi16
  conv_silu_kernel<<<dim3(4, 1024 / CT, 4), 256, 0, stream>>>(
      xiraw, f_conv_w, f_conv_b, b_conv_w, b_conv_b, xi16);

  // 4) G2 split-K x4 + reduce -> xdbl
  g2_kernel<<<dim3(4, 32, 2), 256, 0, stream>>>(xi16, xprF, xprB, part2);
  g2red_kernel<<<dim3(256), 256, 0, stream>>>((const float4*)part2, (float4*)xdbl);

  // 5) delta precompute (bf16)
  delta_kernel<<<dim3(4, 128, 2), 256, 0, stream>>>(
      xdbl, f_dt_w, f_dt_b, b_dt_w, b_dt_b, delta16);

  // 6) chunked scan: pass1 -> combine -> pass3
  scan_part1<<<dim3(4, NC, 4), 256, 0, stream>>>(
      delta16, xi16, xdbl, f_A_log, b_A_log, (float4*)aProd, (float4*)hPart);
  scan_combine<<<dim3(256), 256, 0, stream>>>(aProd, hPart, hInB);
  scan_part3<<<dim3(4, NC, 4), 256, 0, stream>>>(
      delta16, xi16, xdbl, gatebf, f_A_log, b_A_log, f_D, b_D, hInB, ybf);

  // 7) G4: fused_in[:, dir*512:+512] = y @ out_w^T  (N=512, K=1024), 64-row tiles
  gemm_bt<__bf16, false, false, 2><<<dim3(4, 32, 2), 256, 0, stream>>>(
      ybf, (long long)2048 * 1024, wOutF, wOutB, fin, 512LL, 1024, 512, 1024,
      nullptr, nullptr, 0);

  // 8) G5: r = x + fused_in @ fusion_w^T + fusion_b  (N=512, K=1024), 64-row tiles
  gemm_bt<float, true, true, 2><<<dim3(4, 32, 1), 256, 0, stream>>>(
      fin, 0LL, wFus, wFus, rbuf, 0LL, 512, 512, 1024,
      fusion_b, x, 512);

  // 9) LayerNorm -> d_out
  ln_kernel<<<2048, 256, 0, stream>>>(rbuf, ln_g, ln_b, (float*)d_out);
}